// Round 10
// baseline (141.685 us; speedup 1.0000x reference)
//
#include <hip/hip_runtime.h>
#include <hip/hip_bf16.h>
#include <math.h>

typedef __hip_bfloat16 bf16;
typedef __attribute__((ext_vector_type(8))) short bf16x8;
typedef __attribute__((ext_vector_type(4))) float f32x4;
typedef __attribute__((ext_vector_type(16))) float f32x16;

#define DI static __device__ __forceinline__

constexpr int NB = 1024;   // batch
constexpr int ND = 1024;   // latent dim (= out dim)
constexpr int NP = 16;     // parts
constexpr int BKT = 32;    // K-step per tile
constexpr int NKT = ND / BKT;  // 32

DI float gelu_exact(float x) {
    return 0.5f * x * (1.0f + erff(x * 0.70710678118654752f));
}

DI ushort bf16_bits(float f) {
    bf16 h = __float2bfloat16(f);
    return *reinterpret_cast<ushort*>(&h);
}

// ---------- fused pack (R9 form; ~76% of mixed-stream ceiling) ----------
__global__ __launch_bounds__(256) void pack_kernel(const float* __restrict__ x,
                                                   const float* __restrict__ w,
                                                   bf16* __restrict__ xp,
                                                   bf16* __restrict__ wp) {
    __shared__ ushort lds[16][268];
    const int t = threadIdx.x;
    if (blockIdx.x < 4096) {
        const int b = blockIdx.x >> 2;
        const int q = blockIdx.x & 3;            // d-quarter: d0 = q*256
        const float* xb = x + ((size_t)b * ND + q * 256) * NP;
        float4 va[2], vb[2];
#pragma unroll
        for (int it = 0; it < 2; ++it) {
            const int u  = it * 256 + t;
            const int dh = u >> 2;
            const int p0 = (u & 3) * 4;
            va[it] = *reinterpret_cast<const float4*>(&xb[(size_t)(dh * 2)     * NP + p0]);
            vb[it] = *reinterpret_cast<const float4*>(&xb[(size_t)(dh * 2 + 1) * NP + p0]);
        }
        __builtin_amdgcn_sched_barrier(0);
#pragma unroll
        for (int it = 0; it < 2; ++it) {
            const int u  = it * 256 + t;
            const int dh = u >> 2;
            const int p0 = (u & 3) * 4;
            const float a0[4] = { va[it].x, va[it].y, va[it].z, va[it].w };
            const float a1[4] = { vb[it].x, vb[it].y, vb[it].z, vb[it].w };
#pragma unroll
            for (int k = 0; k < 4; ++k) {
                const uint packed = (uint)bf16_bits(a0[k]) | ((uint)bf16_bits(a1[k]) << 16);
                *reinterpret_cast<uint*>(&lds[p0 + k][dh * 2]) = packed;
            }
        }
        __syncthreads();
        const int p = t >> 4, j = t & 15;
        bf16* dst = xp + (size_t)p * (NB * ND) + (size_t)b * ND + q * 256;
#pragma unroll
        for (int it = 0; it < 2; ++it) {
            const int c = it * 16 + j;
            *reinterpret_cast<bf16x8*>(&dst[c * 8]) =
                *reinterpret_cast<const bf16x8*>(&lds[p][c * 8]);
        }
    } else {
        const size_t base = (size_t)(blockIdx.x - 4096) * 4096;
        float4 f[4];
#pragma unroll
        for (int k = 0; k < 4; ++k)
            f[k] = *reinterpret_cast<const float4*>(&w[base + (size_t)k * 1024 + t * 4]);
        __builtin_amdgcn_sched_barrier(0);
#pragma unroll
        for (int k = 0; k < 4; ++k) {
            alignas(8) bf16 tmp[4] = { __float2bfloat16(f[k].x), __float2bfloat16(f[k].y),
                                       __float2bfloat16(f[k].z), __float2bfloat16(f[k].w) };
            *reinterpret_cast<uint2*>(&wp[base + (size_t)k * 1024 + t * 4]) =
                *reinterpret_cast<const uint2*>(tmp);
        }
    }
}

// ---------- grouped GEMM: 256x256, 8 waves, 32x32x16 MFMA ----------
// A in REGISTERS direct from global (each wave's 128 A-rows are private to it;
// double-buffered aA/aB, issued 2 K-tiles ahead, counted vmcnt) — removes 2/3
// of LDS read traffic and 4 of 5 barriers per K-step. B stays on the proven
// gload_lds + swizzle path (triple-buffered, 48 KB LDS).
// Per-kt vmem issue order: 8x A-dwordx4(kt+2), 2x B-gload(kt+2). Boundary
// vmcnt(10) retires the PREVIOUS kt's 10 issues => A(kt+1) regs + B(kt+1) LDS
// resident; barrier publishes B across waves.
__global__ __launch_bounds__(512, 1) void gemm8_kernel(const bf16* __restrict__ xp,
                                                       const bf16* __restrict__ wp,
                                                       bf16* __restrict__ y) {
    __shared__ bf16 Bs[3][256 * BKT];
    const int i = blockIdx.x;
    const int p    = ((i & 7) << 1) | ((i >> 3) & 1);   // part -> XCD i&7
    const int tile = i >> 4;                             // 0..15
    const int bt = (tile >> 2) * 256;
    const int ot = (tile & 3) * 256;
    const bf16* A  = xp + (size_t)p * NB * ND;   // [B][D]
    const bf16* Bm = wp + (size_t)p * ND * ND;   // [O][D]
    const int t = threadIdx.x;
    const int l = t & 63, w = t >> 6;            // 8 waves
    const int wr = w >> 2, wc = w & 3;           // 2(M) x 4(N): wave tile 128x64
    const int lr32 = l & 31, g2 = l >> 5;        // mfma row / k-half

    f32x16 acc[4][2] = {};
    bf16x8 aA[8], aB[8];                          // named double buffers (rule 20)

    auto stageB = [&](int buf, int kt) {
#pragma unroll
        for (int q = 0; q < 2; ++q) {
            const int s   = (q * 8 + w) * 64 + l;
            const int row = s >> 2;
            const int cb  = (s & 3) ^ ((row >> 1) & 3);
            const bf16* gsrc = Bm + (size_t)(ot + row) * ND + kt * BKT + cb * 8;
            bf16* ldst = &Bs[buf][(q * 8 + w) * 512];
            __builtin_amdgcn_global_load_lds((const __attribute__((address_space(1))) void*)gsrc,
                                             (__attribute__((address_space(3))) void*)ldst, 16, 0, 0);
        }
    };
    auto loadA = [&](int kt, bf16x8 (&r)[8]) {
#pragma unroll
        for (int m = 0; m < 4; ++m)
#pragma unroll
            for (int s = 0; s < 2; ++s)
                r[m * 2 + s] = *reinterpret_cast<const bf16x8*>(
                    &A[(size_t)(bt + wr * 128 + m * 32 + lr32) * ND + kt * BKT + (s * 2 + g2) * 8]);
    };
    auto readB = [&](int buf, int n, int s) -> bf16x8 {
        const int row  = wc * 64 + n * 32 + lr32;
        const int ch   = s * 2 + g2;
        const int slot = row * 4 + (ch ^ ((row >> 1) & 3));
        return *reinterpret_cast<const bf16x8*>(&Bs[buf][slot * 8]);
    };

#define GEMM_BODY(K, AR)                                                              \
    {                                                                                 \
        const int c_ = (K) % 3;                                                       \
        bf16x8 bfr[2];                                                                \
        bfr[0] = readB(c_, 0, 0); bfr[1] = readB(c_, 1, 0);                           \
        __builtin_amdgcn_s_setprio(1);                                                \
        _Pragma("unroll")                                                             \
        for (int m = 0; m < 4; ++m) {                                                 \
            acc[m][0] = __builtin_amdgcn_mfma_f32_32x32x16_bf16(AR[m*2], bfr[0], acc[m][0], 0, 0, 0); \
            acc[m][1] = __builtin_amdgcn_mfma_f32_32x32x16_bf16(AR[m*2], bfr[1], acc[m][1], 0, 0, 0); \
        }                                                                             \
        __builtin_amdgcn_s_setprio(0);                                                \
        bfr[0] = readB(c_, 0, 1); bfr[1] = readB(c_, 1, 1);                           \
        __builtin_amdgcn_s_setprio(1);                                                \
        _Pragma("unroll")                                                             \
        for (int m = 0; m < 4; ++m) {                                                 \
            acc[m][0] = __builtin_amdgcn_mfma_f32_32x32x16_bf16(AR[m*2+1], bfr[0], acc[m][0], 0, 0, 0); \
            acc[m][1] = __builtin_amdgcn_mfma_f32_32x32x16_bf16(AR[m*2+1], bfr[1], acc[m][1], 0, 0, 0); \
        }                                                                             \
        __builtin_amdgcn_s_setprio(0);                                                \
        if ((K) + 2 < NKT) { loadA((K) + 2, AR); stageB(((K) + 2) % 3, (K) + 2); }    \
        if ((K) + 1 < NKT) {                                                          \
            if ((K) + 2 < NKT) asm volatile("s_waitcnt vmcnt(10)" ::: "memory");      \
            else               asm volatile("s_waitcnt vmcnt(0)"  ::: "memory");      \
            __builtin_amdgcn_s_barrier();                                             \
            __builtin_amdgcn_sched_barrier(0);                                        \
        }                                                                             \
    }

    // prologue: tiles 0,1 in flight (20 vmem); retire tile 0 (A regs + B LDS)
    loadA(0, aA); stageB(0, 0);
    loadA(1, aB); stageB(1, 1);
    asm volatile("s_waitcnt vmcnt(10)" ::: "memory");
    __builtin_amdgcn_s_barrier();
    __builtin_amdgcn_sched_barrier(0);

#pragma unroll 1
    for (int kt = 0; kt < NKT; kt += 2) {
        GEMM_BODY(kt, aA);
        GEMM_BODY(kt + 1, aB);
    }
#undef GEMM_BODY

    // epilogue: 32x32 C/D layout col = l&31, row = (reg&3) + 8*(reg>>2) + 4*(l>>5)
    bf16* yp = y + (size_t)p * NB * ND;
#pragma unroll
    for (int m = 0; m < 4; ++m) {
#pragma unroll
        for (int n = 0; n < 2; ++n) {
#pragma unroll
            for (int reg = 0; reg < 16; ++reg) {
                const int row = bt + wr * 128 + m * 32 + (reg & 3) + 8 * (reg >> 2) + 4 * g2;
                const int col = ot + wc * 64 + n * 32 + lr32;
                yp[(size_t)row * ND + col] = __float2bfloat16(acc[m][n][reg]);
            }
        }
    }
}

// ---------- y [P][B][O] bf16 (raw) -> out [B][O][P] f32 with exact GELU ----------
__global__ __launch_bounds__(256) void unpack_kernel(const bf16* __restrict__ y,
                                                     float* __restrict__ out) {
    const size_t gidx = (size_t)blockIdx.x * 256 + threadIdx.x;  // (b,o) index
    const size_t o = gidx & 1023;
    const size_t b = gidx >> 10;
    const bf16* yb = y + b * (size_t)ND + o;
    float v[16];
#pragma unroll
    for (int p = 0; p < 16; ++p)
        v[p] = gelu_exact(__bfloat162float(yb[(size_t)p * (NB * ND)]));
    float4* dst = reinterpret_cast<float4*>(out + gidx * NP);
#pragma unroll
    for (int q = 0; q < 4; ++q)
        dst[q] = make_float4(v[q * 4], v[q * 4 + 1], v[q * 4 + 2], v[q * 4 + 3]);
}

// ---------- fallback: pure-f32 tiled GEMM (tiny ws) ----------
__global__ __launch_bounds__(256) void fallback_kernel(const float* __restrict__ x,
                                                       const float* __restrict__ w,
                                                       float* __restrict__ out) {
    __shared__ float As[64][17];
    __shared__ float Bs[64][17];
    const int p = blockIdx.z, bt = blockIdx.y * 64, ot = blockIdx.x * 64;
    const int t = threadIdx.x;
    const int tx = t & 15, ty = t >> 4;
    float acc[4][4] = {};
    for (int k0 = 0; k0 < ND; k0 += 16) {
        __syncthreads();
#pragma unroll
        for (int i = 0; i < 4; ++i) {
            const int idx = i * 256 + t;
            const int r = idx >> 4, k = idx & 15;
            As[r][k] = x[((size_t)(bt + r) * ND + k0 + k) * NP + p];
            Bs[r][k] = w[(size_t)p * ND * ND + (size_t)(ot + r) * ND + k0 + k];
        }
        __syncthreads();
#pragma unroll
        for (int k = 0; k < 16; ++k) {
            float a[4], bb[4];
#pragma unroll
            for (int i = 0; i < 4; ++i) a[i] = As[ty * 4 + i][k];
#pragma unroll
            for (int j = 0; j < 4; ++j) bb[j] = Bs[tx * 4 + j][k];
#pragma unroll
            for (int i = 0; i < 4; ++i)
#pragma unroll
                for (int j = 0; j < 4; ++j) acc[i][j] += a[i] * bb[j];
        }
    }
#pragma unroll
    for (int i = 0; i < 4; ++i)
#pragma unroll
        for (int j = 0; j < 4; ++j)
            out[((size_t)(bt + ty * 4 + i) * ND + (ot + tx * 4 + j)) * NP + p] =
                gelu_exact(acc[i][j]);
}

extern "C" void kernel_launch(void* const* d_in, const int* in_sizes, int n_in,
                              void* d_out, int out_size, void* d_ws, size_t ws_size,
                              hipStream_t stream) {
    const float* x = (const float*)d_in[0];
    const float* w = (const float*)d_in[1];
    float* out = (float*)d_out;

    const size_t nElem     = (size_t)NP * NB * ND;            // 16M
    const size_t packBytes = nElem * sizeof(bf16) * 2;        // 64 MiB (xp + wp)
    const size_t yBytes    = nElem * sizeof(bf16);            // 32 MiB (bf16 y)

    if (ws_size >= packBytes + yBytes) {
        bf16* xp = (bf16*)d_ws;
        bf16* wp = xp + nElem;
        bf16* y  = (bf16*)((char*)d_ws + packBytes);
        pack_kernel<<<8192, 256, 0, stream>>>(x, w, xp, wp);
        gemm8_kernel<<<256, 512, 0, stream>>>(xp, wp, y);
        unpack_kernel<<<(int)(NB * ND / 256), 256, 0, stream>>>(y, out);
    } else {
        fallback_kernel<<<dim3(16, 16, 16), 256, 0, stream>>>(x, w, out);
    }
}

// Round 11
// 111.183 us; speedup vs baseline: 1.2743x; 1.2743x over previous
//
#include <hip/hip_runtime.h>
#include <hip/hip_bf16.h>
#include <math.h>

typedef __hip_bfloat16 bf16;
typedef __attribute__((ext_vector_type(8))) short bf16x8;
typedef __attribute__((ext_vector_type(4))) float f32x4;
typedef __attribute__((ext_vector_type(16))) float f32x16;

#define DI static __device__ __forceinline__

constexpr int NB = 1024;   // batch
constexpr int ND = 1024;   // latent dim (= out dim)
constexpr int NP = 16;     // parts
constexpr int BKT = 32;    // K-step per tile
constexpr int NKT = ND / BKT;  // 32

DI float gelu_exact(float x) {
    return 0.5f * x * (1.0f + erff(x * 0.70710678118654752f));
}

DI ushort bf16_bits(float f) {
    bf16 h = __float2bfloat16(f);
    return *reinterpret_cast<ushort*>(&h);
}

// ---------- fused pack, asm-batched loads ----------
// blocks [0, 2048): x [B,D,P] f32 -> xp [P][B][D] bf16 via LDS transpose.
//   One block = (b, half of D): 512 d x 16 p = 32 KB read; LDS 16.8 KB.
//   8 inline-asm global_load_dwordx4 guaranteed in flight, ONE vmcnt(0)
//   before consumption (compiler re-merges compiler-generated loads with
//   consumers even across sched_barrier -> ~1 outstanding; asm forces batch).
// blocks [2048, 4096): W f32 -> wp bf16, 32 floats/thread, same discipline.
__global__ __launch_bounds__(256) void pack_kernel(const float* __restrict__ x,
                                                   const float* __restrict__ w,
                                                   bf16* __restrict__ xp,
                                                   bf16* __restrict__ wp) {
    __shared__ ushort lds[16][524];              // row 1048B; phase-1 writes 2-way (free)
    const int t = threadIdx.x;
    if (blockIdx.x < 2048) {
        const int b = blockIdx.x >> 1;
        const int h = blockIdx.x & 1;            // d-half: d0 = h*512
        const float* xb = x + ((size_t)b * ND + h * 512) * NP;
        f32x4 va[4], vb[4];
#pragma unroll
        for (int it = 0; it < 4; ++it) {
            const int u  = it * 256 + t;         // 0..1023
            const int dh = u >> 2;               // d-pair 0..255
            const int p0 = (u & 3) * 4;
            const float* pa = &xb[(size_t)(dh * 2)     * NP + p0];
            const float* pb = &xb[(size_t)(dh * 2 + 1) * NP + p0];
            asm volatile("global_load_dwordx4 %0, %2, off\n\t"
                         "global_load_dwordx4 %1, %3, off"
                         : "=&v"(va[it]), "=&v"(vb[it])
                         : "v"(pa), "v"(pb));
        }
        asm volatile("s_waitcnt vmcnt(0)" ::: "memory");
        __builtin_amdgcn_sched_barrier(0);
#pragma unroll
        for (int it = 0; it < 4; ++it) {
            const int u  = it * 256 + t;
            const int dh = u >> 2;
            const int p0 = (u & 3) * 4;
#pragma unroll
            for (int k = 0; k < 4; ++k) {
                const uint packed = (uint)bf16_bits(va[it][k]) |
                                    ((uint)bf16_bits(vb[it][k]) << 16);
                *reinterpret_cast<uint*>(&lds[p0 + k][dh * 2]) = packed;
            }
        }
        __syncthreads();
        const int p = t >> 4, j = t & 15;
        bf16* dst = xp + (size_t)p * (NB * ND) + (size_t)b * ND + h * 512;
#pragma unroll
        for (int it = 0; it < 4; ++it) {
            const int c = it * 16 + j;           // 0..63 chunks of 8 bf16
            *reinterpret_cast<bf16x8*>(&dst[c * 8]) =
                *reinterpret_cast<const bf16x8*>(&lds[p][c * 8]);
        }
    } else {
        // W convert: block covers 8192 consecutive floats (256 thr x 32)
        const size_t base = (size_t)(blockIdx.x - 2048) * 8192;
        const float* wb = w + base;
        f32x4 f[8];
#pragma unroll
        for (int k = 0; k < 8; ++k) {
            const float* pk = &wb[(size_t)k * 1024 + t * 4];
            asm volatile("global_load_dwordx4 %0, %1, off" : "=&v"(f[k]) : "v"(pk));
        }
        asm volatile("s_waitcnt vmcnt(0)" ::: "memory");
        __builtin_amdgcn_sched_barrier(0);
#pragma unroll
        for (int k = 0; k < 8; ++k) {
            alignas(8) bf16 tmp[4] = { __float2bfloat16(f[k][0]), __float2bfloat16(f[k][1]),
                                       __float2bfloat16(f[k][2]), __float2bfloat16(f[k][3]) };
            *reinterpret_cast<uint2*>(&wp[base + (size_t)k * 1024 + t * 4]) =
                *reinterpret_cast<const uint2*>(tmp);
        }
    }
}

// ---------- grouped GEMM (R8 proven form): 256x256, 8 waves, 32x32x16 MFMA ----------
// Triple-buffered LDS; steady-state wait = vmcnt(4), never 0 until the tail.
// LDS rows 64B (4 chunks of 16B); swizzle involution: chunk ^= (row>>1)&3,
// applied to the GLOBAL source (linear LDS dest, rule 21) and to ds_read.
__global__ __launch_bounds__(512, 2) void gemm8_kernel(const bf16* __restrict__ xp,
                                                       const bf16* __restrict__ wp,
                                                       bf16* __restrict__ y) {
    __shared__ bf16 As[3][256 * BKT];
    __shared__ bf16 Bs[3][256 * BKT];
    const int i = blockIdx.x;
    const int p    = ((i & 7) << 1) | ((i >> 3) & 1);   // part -> XCD i&7
    const int tile = i >> 4;                             // 0..15
    const int bt = (tile >> 2) * 256;
    const int ot = (tile & 3) * 256;
    const bf16* A  = xp + (size_t)p * NB * ND;   // [B][D]
    const bf16* Bm = wp + (size_t)p * ND * ND;   // [O][D]
    const int t = threadIdx.x;
    const int l = t & 63, w = t >> 6;            // 8 waves
    const int wr = w >> 2, wc = w & 3;           // 2(M) x 4(N): wave tile 128x64
    const int lr32 = l & 31, g2 = l >> 5;        // mfma row / k-half

    f32x16 acc[4][2] = {};                       // 4 m-tiles x 2 n-tiles of 32x32

    auto stage = [&](int buf, int kt, int q) {
        const int s   = ((q & 1) * 8 + w) * 64 + l;     // 16B slot 0..1023
        const int row = s >> 2;                          // 0..255
        const int cb  = (s & 3) ^ ((row >> 1) & 3);      // inverse-swizzled chunk
        const bf16* gsrc = (q < 2 ? A + (size_t)(bt + row) * ND
                                  : Bm + (size_t)(ot + row) * ND) + kt * BKT + cb * 8;
        bf16* ldst = (q < 2 ? &As[buf][((q & 1) * 8 + w) * 512]
                            : &Bs[buf][((q & 1) * 8 + w) * 512]);
        __builtin_amdgcn_global_load_lds((const __attribute__((address_space(1))) void*)gsrc,
                                         (__attribute__((address_space(3))) void*)ldst, 16, 0, 0);
    };
    auto readA = [&](int buf, int m, int s) -> bf16x8 {
        const int row  = wr * 128 + m * 32 + lr32;
        const int ch   = s * 2 + g2;
        const int slot = row * 4 + (ch ^ ((row >> 1) & 3));
        return *reinterpret_cast<const bf16x8*>(&As[buf][slot * 8]);
    };
    auto readB = [&](int buf, int n, int s) -> bf16x8 {
        const int row  = wc * 64 + n * 32 + lr32;
        const int ch   = s * 2 + g2;
        const int slot = row * 4 + (ch ^ ((row >> 1) & 3));
        return *reinterpret_cast<const bf16x8*>(&Bs[buf][slot * 8]);
    };

#pragma unroll
    for (int q = 0; q < 4; ++q) stage(0, 0, q);
#pragma unroll
    for (int q = 0; q < 4; ++q) stage(1, 1, q);
    asm volatile("s_waitcnt vmcnt(4)" ::: "memory");
    __builtin_amdgcn_s_barrier();
    __builtin_amdgcn_sched_barrier(0);

    int bufc = 0, bufs = 2;
#pragma unroll 1
    for (int kt = 0; kt < NKT; ++kt) {
        // ---- phase 0: k-step 0 frags ; stage A of tile kt+2 ----
        bf16x8 bfr[2], af[4];
#pragma unroll
        for (int n = 0; n < 2; ++n) bfr[n] = readB(bufc, n, 0);
#pragma unroll
        for (int m = 0; m < 4; ++m) af[m] = readA(bufc, m, 0);
        if (kt + 2 < NKT) { stage(bufs, kt + 2, 0); stage(bufs, kt + 2, 1); }
        __builtin_amdgcn_s_barrier();
        asm volatile("s_waitcnt lgkmcnt(0)" ::: "memory");
        __builtin_amdgcn_s_setprio(1);
#pragma unroll
        for (int m = 0; m < 4; ++m)
#pragma unroll
            for (int n = 0; n < 2; ++n)
                acc[m][n] = __builtin_amdgcn_mfma_f32_32x32x16_bf16(af[m], bfr[n], acc[m][n], 0, 0, 0);
        __builtin_amdgcn_s_setprio(0);
        __builtin_amdgcn_s_barrier();
        // ---- phase 1: k-step 1 frags ; stage B of tile kt+2 ----
#pragma unroll
        for (int n = 0; n < 2; ++n) bfr[n] = readB(bufc, n, 1);
#pragma unroll
        for (int m = 0; m < 4; ++m) af[m] = readA(bufc, m, 1);
        if (kt + 2 < NKT) { stage(bufs, kt + 2, 2); stage(bufs, kt + 2, 3); }
        __builtin_amdgcn_s_barrier();
        asm volatile("s_waitcnt lgkmcnt(0)" ::: "memory");
        __builtin_amdgcn_s_setprio(1);
#pragma unroll
        for (int m = 0; m < 4; ++m)
#pragma unroll
            for (int n = 0; n < 2; ++n)
                acc[m][n] = __builtin_amdgcn_mfma_f32_32x32x16_bf16(af[m], bfr[n], acc[m][n], 0, 0, 0);
        __builtin_amdgcn_s_setprio(0);
        if (kt < NKT - 1) {
            if (kt + 2 < NKT) asm volatile("s_waitcnt vmcnt(4)" ::: "memory");
            else              asm volatile("s_waitcnt vmcnt(0)" ::: "memory");
            __builtin_amdgcn_s_barrier();
            __builtin_amdgcn_sched_barrier(0);
        }
        bufc = (bufc == 2) ? 0 : bufc + 1;
        bufs = (bufs == 2) ? 0 : bufs + 1;
    }

    // epilogue: 32x32 C/D layout col = l&31, row = (reg&3) + 8*(reg>>2) + 4*(l>>5)
    bf16* yp = y + (size_t)p * NB * ND;
#pragma unroll
    for (int m = 0; m < 4; ++m) {
#pragma unroll
        for (int n = 0; n < 2; ++n) {
#pragma unroll
            for (int reg = 0; reg < 16; ++reg) {
                const int row = bt + wr * 128 + m * 32 + (reg & 3) + 8 * (reg >> 2) + 4 * g2;
                const int col = ot + wc * 64 + n * 32 + lr32;
                yp[(size_t)row * ND + col] = __float2bfloat16(acc[m][n][reg]);
            }
        }
    }
}

// ---------- y [P][B][O] bf16 (raw) -> out [B][O][P] f32 with exact GELU ----------
__global__ __launch_bounds__(256) void unpack_kernel(const bf16* __restrict__ y,
                                                     float* __restrict__ out) {
    const size_t gidx = (size_t)blockIdx.x * 256 + threadIdx.x;  // (b,o) index
    const size_t o = gidx & 1023;
    const size_t b = gidx >> 10;
    const bf16* yb = y + b * (size_t)ND + o;
    float v[16];
#pragma unroll
    for (int p = 0; p < 16; ++p)
        v[p] = gelu_exact(__bfloat162float(yb[(size_t)p * (NB * ND)]));
    float4* dst = reinterpret_cast<float4*>(out + gidx * NP);
#pragma unroll
    for (int q = 0; q < 4; ++q)
        dst[q] = make_float4(v[q * 4], v[q * 4 + 1], v[q * 4 + 2], v[q * 4 + 3]);
}

// ---------- fallback: pure-f32 tiled GEMM (tiny ws) ----------
__global__ __launch_bounds__(256) void fallback_kernel(const float* __restrict__ x,
                                                       const float* __restrict__ w,
                                                       float* __restrict__ out) {
    __shared__ float As[64][17];
    __shared__ float Bs[64][17];
    const int p = blockIdx.z, bt = blockIdx.y * 64, ot = blockIdx.x * 64;
    const int t = threadIdx.x;
    const int tx = t & 15, ty = t >> 4;
    float acc[4][4] = {};
    for (int k0 = 0; k0 < ND; k0 += 16) {
        __syncthreads();
#pragma unroll
        for (int i = 0; i < 4; ++i) {
            const int idx = i * 256 + t;
            const int r = idx >> 4, k = idx & 15;
            As[r][k] = x[((size_t)(bt + r) * ND + k0 + k) * NP + p];
            Bs[r][k] = w[(size_t)p * ND * ND + (size_t)(ot + r) * ND + k0 + k];
        }
        __syncthreads();
#pragma unroll
        for (int k = 0; k < 16; ++k) {
            float a[4], bb[4];
#pragma unroll
            for (int i = 0; i < 4; ++i) a[i] = As[ty * 4 + i][k];
#pragma unroll
            for (int j = 0; j < 4; ++j) bb[j] = Bs[tx * 4 + j][k];
#pragma unroll
            for (int i = 0; i < 4; ++i)
#pragma unroll
                for (int j = 0; j < 4; ++j) acc[i][j] += a[i] * bb[j];
        }
    }
#pragma unroll
    for (int i = 0; i < 4; ++i)
#pragma unroll
        for (int j = 0; j < 4; ++j)
            out[((size_t)(bt + ty * 4 + i) * ND + (ot + tx * 4 + j)) * NP + p] =
                gelu_exact(acc[i][j]);
}

extern "C" void kernel_launch(void* const* d_in, const int* in_sizes, int n_in,
                              void* d_out, int out_size, void* d_ws, size_t ws_size,
                              hipStream_t stream) {
    const float* x = (const float*)d_in[0];
    const float* w = (const float*)d_in[1];
    float* out = (float*)d_out;

    const size_t nElem     = (size_t)NP * NB * ND;            // 16M
    const size_t packBytes = nElem * sizeof(bf16) * 2;        // 64 MiB (xp + wp)
    const size_t yBytes    = nElem * sizeof(bf16);            // 32 MiB (bf16 y)

    if (ws_size >= packBytes + yBytes) {
        bf16* xp = (bf16*)d_ws;
        bf16* wp = xp + nElem;
        bf16* y  = (bf16*)((char*)d_ws + packBytes);
        pack_kernel<<<4096, 256, 0, stream>>>(x, w, xp, wp);
        gemm8_kernel<<<256, 512, 0, stream>>>(xp, wp, y);
        unpack_kernel<<<(int)(NB * ND / 256), 256, 0, stream>>>(y, out);
    } else {
        fallback_kernel<<<dim3(16, 16, 16), 256, 0, stream>>>(x, w, out);
    }
}